// Round 5
// baseline (4636.534 us; speedup 1.0000x reference)
//
#include <hip/hip_runtime.h>
#include <math.h>

#define TT 96
#define VV 32000
#define EPSF 1e-8f

typedef __attribute__((ext_vector_type(8))) short short8;
typedef __attribute__((ext_vector_type(4))) float f4v;

__device__ __forceinline__ float wsum64(float v){
  #pragma unroll
  for (int m=32;m>0;m>>=1) v += __shfl_xor(v,m);
  return v;
}
__device__ __forceinline__ float sigm(float x){ return 1.0f/(1.0f+expf(-x)); }
__device__ __forceinline__ float softplus(float x){ return x>20.0f ? x : log1pf(expf(x)); }
__device__ __forceinline__ float bf2f(unsigned short u){ return __uint_as_float(((unsigned)u)<<16); }
__device__ __forceinline__ unsigned short f2bf(float f){
  unsigned u = __float_as_uint(f);
  return (unsigned short)((u + 0x7fffu + ((u>>16)&1u)) >> 16);
}

// Device-coherent (cache-bypassing) relaxed ops for cross-wg data.
__device__ __forceinline__ void st_dc(float* p, float v){
  __hip_atomic_store(p, v, __ATOMIC_RELAXED, __HIP_MEMORY_SCOPE_AGENT);
}
__device__ __forceinline__ void st_dc_i(int* p, int v){
  __hip_atomic_store(p, v, __ATOMIC_RELAXED, __HIP_MEMORY_SCOPE_AGENT);
}
__device__ __forceinline__ int ld_dc_i(const int* p){
  return __hip_atomic_load(p, __ATOMIC_RELAXED, __HIP_MEMORY_SCOPE_AGENT);
}
__device__ __forceinline__ unsigned ld_cnt(const unsigned* p){
  return __hip_atomic_load(p, __ATOMIC_RELAXED, __HIP_MEMORY_SCOPE_AGENT);
}
__device__ __forceinline__ float2 ld_dc_2(const float* p){
  union { unsigned long long u; float2 f; } cv;
  cv.u = __hip_atomic_load((const unsigned long long*)p, __ATOMIC_RELAXED, __HIP_MEMORY_SCOPE_AGENT);
  return cv.f;
}

// Core: 4 rows/wave, 16 cols (4 col-groups of 4), K-chunk of 512 split over 16 lanes.
__device__ __forceinline__ void core_chunk(
  const float4* __restrict__ w0, const float4* __restrict__ w1,
  const float4* __restrict__ w2, const float4* __restrict__ w3,
  const float4* __restrict__ xl, int l, int g, float (&acc)[4][4])
{
  #pragma unroll
  for (int kt=0; kt<8; kt++){
    int i = kt*16 + l;
    float4 a0=w0[i], a1=w1[i], a2=w2[i], a3=w3[i];
    #pragma unroll
    for (int j=0;j<4;j++){
      float4 x = xl[(4*g+j)*129 + i];
      acc[0][j] += a0.x*x.x + a0.y*x.y + a0.z*x.z + a0.w*x.w;
      acc[1][j] += a1.x*x.x + a1.y*x.y + a1.z*x.z + a1.w*x.w;
      acc[2][j] += a2.x*x.x + a2.y*x.y + a2.z*x.z + a2.w*x.w;
      acc[3][j] += a3.x*x.x + a3.y*x.y + a3.z*x.z + a3.w*x.w;
    }
  }
}

__device__ __forceinline__ float reduce_pick(float (&acc)[4][4], int l){
  float r = 0.f;
  #pragma unroll
  for (int ri=0;ri<4;ri++)
  #pragma unroll
  for (int j=0;j<4;j++){
    float v = acc[ri][j];
    v += __shfl_xor(v,1); v += __shfl_xor(v,2);
    v += __shfl_xor(v,4); v += __shfl_xor(v,8);
    if (l == ri*4+j) r = v;
  }
  return r;
}

// ---------------- phase 1: persistent recurrence, all point-to-point sync ----------------
// 256 wgs x 256 thr. Monotone spread counters, no central barrier:
//   cntA[16 lines]: one add per wg after its h(t+1) store. Pollers: every wg
//     before staging h(t) (tgt 16*t); B before staging h(t+1) (tgt 16*(t+1)).
//   cntB[8 lines]: one add per B-wg after tf store. Poller: C (tgt 8*(t+1)).
//   aall[96][8][64]: C writes ai+1 to 8 replicated copies; A polls copy (wg&7)
//     AFTER core_chunk (overlaps B+C of previous step with A compute).
__global__ __launch_bounds__(256) void k_phase1(
  const float* __restrict__ Whh, float* __restrict__ hall,
  const float* __restrict__ Pw, const float* __restrict__ Pa,
  int* __restrict__ aall, float* __restrict__ c,
  const float* __restrict__ Wf1, const float* __restrict__ cf,
  float* __restrict__ tf,
  const float* __restrict__ Gb, const float* __restrict__ gb0,
  const int* __restrict__ ta, const int* __restrict__ nfp,
  float* __restrict__ loss,
  unsigned* __restrict__ cntA, unsigned* __restrict__ cntB)
{
  __shared__ float4 xl[16*129];
  __shared__ float sg[256];
  __shared__ float sS[64];
  __shared__ int   sai[16];
  int tid = threadIdx.x, lane = tid & 63, wave = tid >> 6;
  int l = lane & 15, g = lane >> 4;
  int wg = blockIdx.x;

  for (int t=0; t<TT; t++){
    // ---- phase A: gates + LSTM pointwise (all wgs) ----
    {
      int j0 = wg*4;
      int r = l>>2;
      int b = g*4 + (l&3);
      int row = wave*1024 + j0 + r;
      // prefetch Pw (independent of all waits; stays in flight)
      float pwv = __builtin_nontemporal_load(Pw + ((size_t)(b*96+t))*4096 + row);
      // wait: h(t) complete (16 spread counters, direct poll, no release hop)
      if (t > 0 && tid < 64){
        unsigned tgt = (unsigned)t * 16u;
        while (true){
          unsigned v = (tid < 16) ? ld_cnt(cntA + tid*64) : tgt;
          if (__all(v >= tgt)) break;
          __builtin_amdgcn_s_sleep(1);
        }
      }
      __syncthreads();
      const float4* h4 = (const float4*)hall + (size_t)t*4096;
      float acc[4][4] = {};
      for (int kc=0; kc<2; kc++){
        for (int idx=tid; idx<2048; idx+=256){
          int bb = idx>>7, i = idx&127;
          xl[bb*129+i] = h4[bb*256 + kc*128 + i];
        }
        __syncthreads();
        const float4* w0 = (const float4*)(Whh + (size_t)(wave*1024 + j0+0)*1024) + kc*128;
        const float4* w1 = (const float4*)(Whh + (size_t)(wave*1024 + j0+1)*1024) + kc*128;
        const float4* w2 = (const float4*)(Whh + (size_t)(wave*1024 + j0+2)*1024) + kc*128;
        const float4* w3 = (const float4*)(Whh + (size_t)(wave*1024 + j0+3)*1024) + kc*128;
        core_chunk(w0,w1,w2,w3, xl, l, g, acc);
        __syncthreads();
      }
      float v = reduce_pick(acc, l);
      // fetch ai(t-1): poll replicated write-once slots (epoch-encoded ai+1)
      if (t > 0 && tid < 64){
        const int* ap = &aall[(t-1)*512 + (wg&7)*64];
        bool need = (tid < 16);
        while (true){
          int vv = need ? ld_dc_i(ap + tid) : 1;
          if (__all(vv != 0)){ if (need) sai[tid] = vv - 1; break; }
          __builtin_amdgcn_s_sleep(1);
        }
      }
      __syncthreads();
      float e = pwv;
      if (t > 0){
        int ai = sai[b];
        e += __builtin_nontemporal_load(Pa + ((size_t)(b*64+ai))*4096 + row);
      }
      sg[wave*64 + r*16 + b] = v + e;
      __syncthreads();
      if (tid < 64){
        int jj = j0 + (tid>>4), bb = tid&15;
        float ig = sg[  0 + (tid>>4)*16 + bb];
        float fg = sg[ 64 + (tid>>4)*16 + bb];
        float gg = sg[128 + (tid>>4)*16 + bb];
        float og = sg[192 + (tid>>4)*16 + bb];
        int ci = bb*1024 + jj;
        float cn = sigm(fg)*c[ci] + sigm(ig)*tanhf(gg);
        c[ci] = cn;   // owner-exclusive: plain cached
        st_dc(&hall[((size_t)(t+1)*16 + bb)*1024 + jj], sigm(og)*tanhf(cn));
      }
      __syncthreads();   // drain h stores (vmcnt 0) before arrival
      if (tid == 0)
        __hip_atomic_fetch_add(cntA + (wg&15)*64, 1u, __ATOMIC_RELAXED, __HIP_MEMORY_SCOPE_AGENT);
    }

    // ---- phase B: tf (wgs 0..63) ----
    if (wg < 64){
      // wait: h(t+1) complete
      if (tid < 64){
        unsigned tgt = (unsigned)(t+1) * 16u;
        while (true){
          unsigned v = (tid < 16) ? ld_cnt(cntA + tid*64) : tgt;
          if (__all(v >= tgt)) break;
          __builtin_amdgcn_s_sleep(1);
        }
      }
      __syncthreads();
      int rl0 = wg*16 + wave*4;
      const float4* h4 = (const float4*)hall + (size_t)(t+1)*4096;
      float acc[4][4] = {};
      for (int kc=0; kc<2; kc++){
        for (int idx=tid; idx<2048; idx+=256){
          int bb = idx>>7, i = idx&127;
          xl[bb*129+i] = h4[bb*256 + kc*128 + i];
        }
        __syncthreads();
        const float4* w0 = (const float4*)(Wf1 + (size_t)(rl0+0)*1536) + kc*128;
        const float4* w1 = (const float4*)(Wf1 + (size_t)(rl0+1)*1536) + kc*128;
        const float4* w2 = (const float4*)(Wf1 + (size_t)(rl0+2)*1536) + kc*128;
        const float4* w3 = (const float4*)(Wf1 + (size_t)(rl0+3)*1536) + kc*128;
        core_chunk(w0,w1,w2,w3, xl, l, g, acc);
        __syncthreads();
      }
      float v = reduce_pick(acc, l);
      int rl = rl0 + (l>>2);
      int b = g*4 + (l&3);
      float* tfb = tf + (t&1)*16384;
      st_dc(&tfb[b*1024 + rl], fmaxf(v + cf[b*1024 + rl], 0.f));
      __syncthreads();   // drain tf stores before signaling
      if (tid == 0)
        __hip_atomic_fetch_add(cntB + (wg&7)*64, 1u, __ATOMIC_RELAXED, __HIP_MEMORY_SCOPE_AGENT);
    }

    // ---- phase C: scores + softmax + argmax + loss (wgs 240..255, b = wg-240) ----
    if (wg >= 240){
      int b = wg - 240;
      if (tid < 64){
        unsigned tgt = (unsigned)(t+1) * 8u;
        while (true){
          unsigned vv = (tid < 8) ? ld_cnt(cntB + tid*64) : tgt;
          if (__all(vv >= tgt)) break;
          __builtin_amdgcn_s_sleep(1);
        }
      }
      __syncthreads();
      const float* tfb = tf + (t&1)*16384;
      float* stf = (float*)xl;
      {
        const float* src = tfb + b*1024;
        float2 c0 = ld_dc_2(src + 4*tid + 0);
        float2 c1 = ld_dc_2(src + 4*tid + 2);
        ((float2*)stf)[2*tid+0] = c0;
        ((float2*)stf)[2*tid+1] = c1;
      }
      __syncthreads();
      int f = tid>>2, q = tid&3;
      const float4* G4 = (const float4*)(Gb + (size_t)(b*64+f)*1024);
      const float4* st4 = (const float4*)stf;
      float acc = 0.f;
      for (int j=0;j<64;j++){
        int i = q*64 + j;
        float4 a = G4[i], x = st4[i];
        acc += a.x*x.x + a.y*x.y + a.z*x.z + a.w*x.w;
      }
      acc += __shfl_xor(acc,1);
      acc += __shfl_xor(acc,2);
      if (q==0) sS[f] = acc + gb0[b*64+f];
      __syncthreads();
      if (tid < 64){
        int nf = nfp[b];
        float s = sS[tid];
        float mx = s;
        #pragma unroll
        for (int m=32;m>0;m>>=1) mx = fmaxf(mx, __shfl_xor(mx,m));
        float p = expf(s - mx);
        float ps = wsum64(p);
        p /= ps;
        bool mask = (tid < nf) || (tid == 63);
        float mval = mask ? (p + EPSF) : EPSF;
        float msum = wsum64(mval);
        float bv = mval; int bi2 = tid;
        #pragma unroll
        for (int m=32;m>0;m>>=1){
          float ov = __shfl_xor(bv,m); int oi = __shfl_xor(bi2,m);
          if (ov > bv || (ov == bv && oi < bi2)){ bv = ov; bi2 = oi; }
        }
        int at = ta[b*TT + t];
        float mat = __shfl(mval, at);
        if (tid == 0){
          atomicAdd(loss, -(logf(mat) - logf(msum)));
          #pragma unroll
          for (int gg2=0; gg2<8; gg2++)
            st_dc_i(&aall[t*512 + gg2*64 + b], bi2 + 1);   // 8 replicated copies
        }
      }
      __syncthreads();   // xl (stf) reuse protection before next step's staging
    }
  }
}

// ---------------- phase 2: batched over all (b,t) ----------------

// tcvp[n] = relu(W{c,v,p}1_h @ h_t + Ph[b,aidx] + bias), n = t*16+b
__global__ __launch_bounds__(256) void k2_cvp(
  const float* __restrict__ Wc1, const float* __restrict__ Wv1,
  const float* __restrict__ Wp1, const float* __restrict__ hall,
  const float* __restrict__ Ph, const int* __restrict__ aall,
  const float* __restrict__ bc1, const float* __restrict__ bv1,
  const float* __restrict__ bp1, float* __restrict__ tcvp)
{
  __shared__ float4 xl[16*129];
  int tid = threadIdx.x, lane = tid & 63, wave = tid >> 6;
  int l = lane & 15, g = lane >> 4;
  int seg = blockIdx.x >> 6;
  int rl0 = (blockIdx.x & 63)*16 + wave*4;
  const float* W = (seg==0)?Wc1:(seg==1)?Wv1:Wp1;
  const float4* h4 = (const float4*)hall + (size_t)(16 + blockIdx.y*16)*256;
  float acc[4][4] = {};
  for (int kc=0; kc<2; kc++){
    for (int idx=tid; idx<2048; idx+=256){
      int cc = idx>>7, i = idx&127;
      xl[cc*129+i] = h4[cc*256 + kc*128 + i];
    }
    __syncthreads();
    const float4* w0 = (const float4*)(W + (size_t)(rl0+0)*1536) + kc*128;
    const float4* w1 = (const float4*)(W + (size_t)(rl0+1)*1536) + kc*128;
    const float4* w2 = (const float4*)(W + (size_t)(rl0+2)*1536) + kc*128;
    const float4* w3 = (const float4*)(W + (size_t)(rl0+3)*1536) + kc*128;
    core_chunk(w0,w1,w2,w3, xl, l, g, acc);
    __syncthreads();
  }
  float v = reduce_pick(acc, l);
  int rl = rl0 + (l>>2);
  int n = blockIdx.y*16 + g*4 + (l&3);
  int b = n & 15;
  int ai = aall[(n>>4)*512 + (n&15)] - 1;
  const float* bias = (seg==0)?bc1:(seg==1)?bv1:bp1;
  float vv = v + Ph[((size_t)(b*64+ai))*3072 + seg*1024 + rl] + bias[rl];
  tcvp[(size_t)n*3072 + seg*1024 + rl] = fmaxf(vv, 0.f);
}

// kvoca(bf16) / kpos / zlog for all n
__global__ __launch_bounds__(256) void k2_heads2(
  const float* __restrict__ Wv2, const float* __restrict__ bv2,
  const float* __restrict__ Wp2, const float* __restrict__ bp2,
  const float* __restrict__ Wc2, const float* __restrict__ bc2,
  const float* __restrict__ tcvp, unsigned short* __restrict__ kvh,
  float* __restrict__ kpall, float* __restrict__ zlall)
{
  __shared__ float4 xl[16*129];
  int tid = threadIdx.x, lane = tid & 63, wave = tid >> 6;
  int l = lane & 15, g = lane >> 4;
  int bx = blockIdx.x;
  int seg = (bx < 32) ? 0 : (bx < 39) ? 1 : 2;
  int rb  = (seg==0) ? bx*16 : (seg==1) ? (bx-32)*16 : 0;
  int rl0 = rb + wave*4;
  const float* WS = (seg==0)?Wv2:(seg==1)?Wp2:Wc2;
  int maxr = (seg==0)?511:(seg==1)?99:0;
  int xoff4 = (seg==0)?256:(seg==1)?512:0;
  const float4* X4 = (const float4*)tcvp;
  float acc[4][4] = {};
  for (int kc=0; kc<2; kc++){
    for (int idx=tid; idx<2048; idx+=256){
      int cc = idx>>7, i = idx&127;
      xl[cc*129+i] = X4[(size_t)(blockIdx.y*16+cc)*768 + xoff4 + kc*128 + i];
    }
    __syncthreads();
    const float4* w0 = (const float4*)(WS + (size_t)min(rl0+0,maxr)*1024) + kc*128;
    const float4* w1 = (const float4*)(WS + (size_t)min(rl0+1,maxr)*1024) + kc*128;
    const float4* w2 = (const float4*)(WS + (size_t)min(rl0+2,maxr)*1024) + kc*128;
    const float4* w3 = (const float4*)(WS + (size_t)min(rl0+3,maxr)*1024) + kc*128;
    core_chunk(w0,w1,w2,w3, xl, l, g, acc);
    __syncthreads();
  }
  float v = reduce_pick(acc, l);
  int rl = rl0 + (l>>2);
  int n = blockIdx.y*16 + g*4 + (l&3);
  if (seg==0) kvh[(size_t)n*512 + rl] = f2bf(v + bv2[rl]);
  else if (seg==1){ if (rl < 100) kpall[n*128 + rl] = v + bp2[rl]; }
  else { if (rl == 0) zlall[n] = v + bc2[0]; }
}

// vocab GEMM (bf16 MFMA, 64x64 per wave) with fused per-64-row logsumexp partials
__global__ __launch_bounds__(256) void k2_vocab(
  const unsigned short* __restrict__ embh, const unsigned short* __restrict__ kvh,
  float2* __restrict__ part)
{
  int wid = blockIdx.x*4 + (threadIdx.x>>6);
  int lane = threadIdx.x & 63;
  int mtile = wid % 500, ntile = wid / 500;
  int mrow = mtile*64 + (lane&15);
  int ncol = ntile*64 + (lane&15);
  int ko = (lane>>4)*8;
  f4v acc[4][4];
  #pragma unroll
  for (int i=0;i<4;i++)
  #pragma unroll
  for (int j=0;j<4;j++)
  #pragma unroll
  for (int r=0;r<4;r++) acc[i][j][r] = 0.f;
  for (int kk=0; kk<512; kk+=32){
    short8 af[4], bfr[4];
    #pragma unroll
    for (int i=0;i<4;i++)
      af[i] = *(const short8*)(embh + (size_t)(mrow+16*i)*512 + kk + ko);
    #pragma unroll
    for (int i=0;i<4;i++)
      bfr[i] = *(const short8*)(kvh + (size_t)(ncol+16*i)*512 + kk + ko);
    #pragma unroll
    for (int i=0;i<4;i++)
      #pragma unroll
      for (int j=0;j<4;j++)
        acc[i][j] = __builtin_amdgcn_mfma_f32_16x16x32_bf16(af[i], bfr[j], acc[i][j], 0,0,0);
  }
  int q = lane>>4;
  #pragma unroll
  for (int j=0;j<4;j++){
    float mx = -3.4e38f;
    #pragma unroll
    for (int i=0;i<4;i++)
    #pragma unroll
    for (int r=0;r<4;r++) mx = fmaxf(mx, acc[i][j][r]);
    mx = fmaxf(mx, __shfl_xor(mx,16));
    mx = fmaxf(mx, __shfl_xor(mx,32));
    float s = 0.f;
    #pragma unroll
    for (int i=0;i<4;i++)
    #pragma unroll
    for (int r=0;r<4;r++) s += expf(acc[i][j][r] - mx);
    s += __shfl_xor(s,16);
    s += __shfl_xor(s,32);
    if (q==0){
      int col = ntile*64 + 16*j + (lane&15);
      part[(size_t)col*500 + mtile] = make_float2(mx, s);
    }
  }
}

// per-n: merge partials -> logZ; direct dot for logit[w]; vocab loss (z==0)
__global__ __launch_bounds__(256) void k2_vfin(
  const float2* __restrict__ part, const unsigned short* __restrict__ embh,
  const unsigned short* __restrict__ kvh, const int* __restrict__ tw,
  const int* __restrict__ tz, float* __restrict__ loss)
{
  __shared__ float red[4];
  int n = blockIdx.x, tid = threadIdx.x;
  int t = n>>4, b = n&15;
  float mx = -3.4e38f;
  for (int i=tid; i<500; i+=256) mx = fmaxf(mx, part[(size_t)n*500+i].x);
  #pragma unroll
  for (int m=32;m>0;m>>=1) mx = fmaxf(mx, __shfl_xor(mx,m));
  if ((tid&63)==0) red[tid>>6] = mx;
  __syncthreads();
  float M = fmaxf(fmaxf(red[0],red[1]), fmaxf(red[2],red[3]));
  __syncthreads();
  float s = 0.f;
  for (int i=tid; i<500; i+=256){
    float2 p = part[(size_t)n*500+i];
    s += p.y * expf(p.x - M);
  }
  s = wsum64(s);
  if ((tid&63)==0) red[tid>>6] = s;
  __syncthreads();
  float S = red[0]+red[1]+red[2]+red[3];
  __syncthreads();
  int w = tw[b*96+t];
  float d = 0.f;
  {
    const unsigned short* er = embh + (size_t)w*512;
    const unsigned short* kr = kvh + (size_t)n*512;
    for (int i=tid; i<512; i+=256) d += bf2f(er[i])*bf2f(kr[i]);
  }
  d = wsum64(d);
  if ((tid&63)==0) red[tid>>6] = d;
  __syncthreads();
  if (tid==0 && tz[b*96+t]==0){
    float D = red[0]+red[1]+red[2]+red[3];
    atomicAdd(loss, -(D - (M + logf(S))));
  }
}

// per-n: z loss + position loss
__global__ __launch_bounds__(128) void k2_posz(
  const float* __restrict__ kpall, const float* __restrict__ zlall,
  const float* __restrict__ WP, const float* __restrict__ bP,
  const float* __restrict__ pmask, const int* __restrict__ tw,
  const int* __restrict__ ta, const int* __restrict__ tz,
  float* __restrict__ loss)
{
  __shared__ float pp[100];
  int n = blockIdx.x, tid = threadIdx.x;
  int t = n>>4, b = n&15;
  if (tid < 100){
    float s = bP[tid];
    const float* wr = WP + tid*100;
    const float* kp = kpall + n*128;
    for (int j=0;j<100;j++) s += wr[j]*kp[j];
    pp[tid] = s;
  }
  __syncthreads();
  if (tid == 0){
    float u = zlall[n];
    int z = tz[b*96+t], w = tw[b*96+t], at = ta[b*96+t];
    float tot = z ? softplus(-u) : softplus(u);
    if (z){
      float mxv = -1e30f;
      for (int l2=0;l2<100;l2++) mxv = fmaxf(mxv, pp[l2]);
      float se = 0.f;
      for (int l2=0;l2<100;l2++) se += expf(pp[l2]-mxv);
      const float* pm = pmask + ((size_t)b*64 + at)*100;
      float msum = 0.f, mw = 0.f;
      for (int l2=0;l2<100;l2++){
        float m = pm[l2]*(expf(pp[l2]-mxv)/se) + EPSF;
        msum += m;
        if (l2==w) mw = m;
      }
      tot += -(logf(mw) - logf(msum));
    }
    atomicAdd(loss, tot);
  }
}

// ---------------- phase 0: once-per-launch precompute ----------------

__global__ void k_cvt_emb(const float* __restrict__ emb, unsigned* __restrict__ out){
  const int n = VV*512/2;
  for (int idx = blockIdx.x*256 + threadIdx.x; idx < n; idx += gridDim.x*256){
    float2 v = ((const float2*)emb)[idx];
    unsigned a = __float_as_uint(v.x), b = __float_as_uint(v.y);
    unsigned ra = (a + 0x7fffu + ((a>>16)&1u)) >> 16;
    unsigned rb = (b + 0x7fffu + ((b>>16)&1u)) >> 16;
    out[idx] = ra | (rb<<16);
  }
}

__global__ void k_setup(const float* __restrict__ fe, const int* __restrict__ nfp,
                        float* __restrict__ e_k){
  int b = blockIdx.x, tid = threadIdx.x;
  int nf = nfp[b];
  for (int d=tid; d<512; d+=256){
    float s = 0.f;
    for (int f=0; f<nf; f++) s += fe[((size_t)b*64+f)*512 + d];
    e_k[b*512+d] = s/(float)nf;
  }
}

__global__ __launch_bounds__(256) void k_pre_pa(
  const float* __restrict__ Wih, const float* __restrict__ fe, float* __restrict__ Pa)
{
  __shared__ float4 xl[16*129];
  int tid = threadIdx.x, lane = tid & 63, wave = tid >> 6;
  int l = lane & 15, g = lane >> 4;
  int row0 = blockIdx.x*16 + wave*4;
  int c0 = blockIdx.y*16;
  const float4* fe4 = (const float4*)fe;
  for (int idx=tid; idx<2048; idx+=256){
    int cc = idx>>7, i = idx&127;
    xl[cc*129+i] = fe4[(size_t)(c0+cc)*128 + i];
  }
  __syncthreads();
  const float4* w0 = (const float4*)(Wih + (size_t)(row0+0)*1124);
  const float4* w1 = (const float4*)(Wih + (size_t)(row0+1)*1124);
  const float4* w2 = (const float4*)(Wih + (size_t)(row0+2)*1124);
  const float4* w3 = (const float4*)(Wih + (size_t)(row0+3)*1124);
  float acc[4][4] = {};
  core_chunk(w0,w1,w2,w3, xl, l, g, acc);
  float v = reduce_pick(acc, l);
  int row = row0 + (l>>2), c = c0 + g*4 + (l&3);
  Pa[(size_t)c*4096 + row] = v;
}

__global__ __launch_bounds__(256) void k_pre_ph(
  const float* __restrict__ Wc1, const float* __restrict__ Wv1,
  const float* __restrict__ Wp1, const float* __restrict__ fe, float* __restrict__ Ph)
{
  __shared__ float4 xl[16*129];
  int tid = threadIdx.x, lane = tid & 63, wave = tid >> 6;
  int l = lane & 15, g = lane >> 4;
  int row0 = blockIdx.x*16 + wave*4;
  int head = row0 >> 10, rl0 = row0 & 1023;
  const float* W = (head==0)?Wc1:(head==1)?Wv1:Wp1;
  int c0 = blockIdx.y*16;
  const float4* fe4 = (const float4*)fe;
  for (int idx=tid; idx<2048; idx+=256){
    int cc = idx>>7, i = idx&127;
    xl[cc*129+i] = fe4[(size_t)(c0+cc)*128 + i];
  }
  __syncthreads();
  const float4* w0 = (const float4*)(W + (size_t)(rl0+0)*1536 + 1024);
  const float4* w1 = (const float4*)(W + (size_t)(rl0+1)*1536 + 1024);
  const float4* w2 = (const float4*)(W + (size_t)(rl0+2)*1536 + 1024);
  const float4* w3 = (const float4*)(W + (size_t)(rl0+3)*1536 + 1024);
  float acc[4][4] = {};
  core_chunk(w0,w1,w2,w3, xl, l, g, acc);
  float v = reduce_pick(acc, l);
  int row = row0 + (l>>2), c = c0 + g*4 + (l&3);
  Ph[(size_t)c*3072 + row] = v;
}

__global__ __launch_bounds__(256) void k_pre_pw(
  const float* __restrict__ Wih, const float* __restrict__ emb,
  const int* __restrict__ tw, const int* __restrict__ tz,
  const float* __restrict__ bih, const float* __restrict__ bhh,
  float* __restrict__ Pw)
{
  __shared__ float4 xl[16*129];
  int tid = threadIdx.x, lane = tid & 63, wave = tid >> 6;
  int l = lane & 15, g = lane >> 4;
  int row0 = blockIdx.x*16 + wave*4;
  int c0 = blockIdx.y*16;
  for (int idx=tid; idx<2048; idx+=256){
    int cc = idx>>7, i = idx&127;
    int c = c0+cc, b = c/96, t2 = c - b*96;
    int w=0, z=0;
    if (t2>0){ w = tw[b*96+t2-1]; z = tz[b*96+t2-1]; }
    float4 v = make_float4(0.f,0.f,0.f,0.f);
    if (z==0) v = ((const float4*)emb)[(size_t)w*128 + i];
    xl[cc*129+i] = v;
  }
  __syncthreads();
  const float4* w0 = (const float4*)(Wih + (size_t)(row0+0)*1124 + 512);
  const float4* w1 = (const float4*)(Wih + (size_t)(row0+1)*1124 + 512);
  const float4* w2 = (const float4*)(Wih + (size_t)(row0+2)*1124 + 512);
  const float4* w3 = (const float4*)(Wih + (size_t)(row0+3)*1124 + 512);
  float acc[4][4] = {};
  core_chunk(w0,w1,w2,w3, xl, l, g, acc);
  float v = reduce_pick(acc, l);
  int row = row0 + (l>>2), c = c0 + g*4 + (l&3);
  int b = c/96, t2 = c - b*96;
  int w=0, z=0;
  if (t2>0){ w = tw[b*96+t2-1]; z = tz[b*96+t2-1]; }
  v += bih[row] + bhh[row];
  if (z) v += Wih[(size_t)row*1124 + 1024 + w];
  Pw[(size_t)c*4096 + row] = v;
}

__global__ __launch_bounds__(256) void k_pre_cf(
  const float* __restrict__ Wf1, const float* __restrict__ bf1,
  const float* __restrict__ e_k, float* __restrict__ cf)
{
  __shared__ float4 xl[16*129];
  int tid = threadIdx.x, lane = tid & 63, wave = tid >> 6;
  int l = lane & 15, g = lane >> 4;
  int row0 = blockIdx.x*16 + wave*4;
  const float4* ek4 = (const float4*)e_k;
  for (int idx=tid; idx<2048; idx+=256){
    int cc = idx>>7, i = idx&127;
    xl[cc*129+i] = ek4[cc*128 + i];
  }
  __syncthreads();
  const float4* w0 = (const float4*)(Wf1 + (size_t)(row0+0)*1536 + 1024);
  const float4* w1 = (const float4*)(Wf1 + (size_t)(row0+1)*1536 + 1024);
  const float4* w2 = (const float4*)(Wf1 + (size_t)(row0+2)*1536 + 1024);
  const float4* w3 = (const float4*)(Wf1 + (size_t)(row0+3)*1536 + 1024);
  float acc[4][4] = {};
  core_chunk(w0,w1,w2,w3, xl, l, g, acc);
  float v = reduce_pick(acc, l);
  int row = row0 + (l>>2), b = g*4 + (l&3);
  cf[b*1024 + row] = v + bf1[row];
}

// Gb[(b*64+f)][k] = sum_d fe[b,f,d] * Wf2[d][k]   (1024 x 1024, K=512)
__global__ __launch_bounds__(256) void k_pre_g(
  const float* __restrict__ Wf2, const float* __restrict__ fe, float* __restrict__ Gb)
{
  __shared__ float fs[16][128];
  int tid = threadIdx.x;
  int r0 = blockIdx.x*16;
  int k0 = blockIdx.y*256;
  float acc[16] = {};
  for (int dc=0; dc<4; dc++){
    for (int idx=tid; idx<2048; idx+=256){
      int r = idx>>7, d = idx&127;
      fs[r][d] = fe[(size_t)(r0+r)*512 + dc*128 + d];
    }
    __syncthreads();
    for (int d=0; d<128; d++){
      float w = Wf2[(size_t)(dc*128+d)*1024 + k0 + tid];
      #pragma unroll
      for (int r=0;r<16;r++) acc[r] += fs[r][d]*w;
    }
    __syncthreads();
  }
  #pragma unroll
  for (int r=0;r<16;r++) Gb[(size_t)(r0+r)*1024 + k0 + tid] = acc[r];
}

// gb0[b,f] = fe[b,f,:] . bf2
__global__ __launch_bounds__(256) void k_gb0(
  const float* __restrict__ fe, const float* __restrict__ bf2, float* __restrict__ gb0)
{
  int b = blockIdx.x;
  int f = threadIdx.x>>2, q = threadIdx.x&3;
  const float4* fe4 = (const float4*)(fe + ((size_t)b*64+f)*512);
  const float4* b4 = (const float4*)bf2;
  float acc = 0.f;
  for (int j=0;j<32;j++){
    int i = q*32+j;
    float4 a = fe4[i], x = b4[i];
    acc += a.x*x.x + a.y*x.y + a.z*x.z + a.w*x.w;
  }
  acc += __shfl_xor(acc,1);
  acc += __shfl_xor(acc,2);
  if (q==0) gb0[b*64+f] = acc;
}

__global__ void k_out(const float* __restrict__ loss, float* __restrict__ out){
  out[0] = loss[0];
}

extern "C" void kernel_launch(void* const* d_in, const int* in_sizes, int n_in,
                              void* d_out, int out_size, void* d_ws, size_t ws_size,
                              hipStream_t stream)
{
  const float* fe   = (const float*)d_in[0];
  const float* pmask= (const float*)d_in[1];
  const float* emb  = (const float*)d_in[2];
  const float* Wih  = (const float*)d_in[3];
  const float* Whh  = (const float*)d_in[4];
  const float* bih  = (const float*)d_in[5];
  const float* bhh  = (const float*)d_in[6];
  const float* Wf1  = (const float*)d_in[7];
  const float* bf1  = (const float*)d_in[8];
  const float* Wf2  = (const float*)d_in[9];
  const float* bf2  = (const float*)d_in[10];
  const float* Wc1  = (const float*)d_in[11];
  const float* bc1  = (const float*)d_in[12];
  const float* Wc2  = (const float*)d_in[13];
  const float* bc2  = (const float*)d_in[14];
  const float* Wv1  = (const float*)d_in[15];
  const float* bv1  = (const float*)d_in[16];
  const float* Wv2  = (const float*)d_in[17];
  const float* bv2  = (const float*)d_in[18];
  const float* Wp1  = (const float*)d_in[19];
  const float* bp1  = (const float*)d_in[20];
  const float* Wp2  = (const float*)d_in[21];
  const float* bp2  = (const float*)d_in[22];
  const float* WP   = (const float*)d_in[23];
  const float* bP   = (const float*)d_in[24];
  const int* tw  = (const int*)d_in[25];
  const int* ta  = (const int*)d_in[26];
  const int* tz  = (const int*)d_in[27];
  const int* nfp = (const int*)d_in[28];

  float* w = (float*)d_ws;
  // layout (float offsets). Counters + c + hall slot0 zeroed by memset1;
  // aall (replicated x8, polled-for-nonzero) zeroed by memset2.
  float*    loss  = w + 0;
  unsigned* cntA  = (unsigned*)(w + 64);          // 16 ctrs, stride 64 (256B)
  unsigned* cntB  = (unsigned*)(w + 1088);        // 8 ctrs, stride 64
  float*    c     = w + 2048;                     // 16384 -> 18432
  float*    hall  = w + 18432;                    // 97*16384 -> 1607680
  int*      aall  = (int*)(w + 1607680);          // 96*512 ints -> 1656832
  float*    tf    = w + 1656832;                  // 2 x 16384 -> 1689600
  float*    gb0   = w + 1689600;                  // 1024 -> 1690624
  float*    e_k   = w + 1690624;                  // 8192 -> 1698816
  float*    cf    = w + 1698816;                  // 16384 -> 1715200
  float*    kpall = w + 1715200;                  // 196608 -> 1911808
  float*    zlall = w + 1911808;                  // 1536 -> 1913344
  float*    tcvp  = w + 1913344;                  // 4718592 -> 6631936 (phase 2 only)
  float*    Gb    = w + 1913344;                  // 1048576 — aliases tcvp; dead before k2_cvp
  float2*   part  = (float2*)(w + 6631936);       // 1536000 floats -> 8167936
  unsigned short* kvh = (unsigned short*)(w + 8167936); // 786432 ushorts -> 8561152
  float*    Pa    = w + 8561152;                  // 4194304 -> 12755456
  float*    Ph    = w + 12755456;                 // 3145728 -> 15901184
  float*    Pw    = w + 15901184;                 // 6291456 -> 22192640
  unsigned* embbf = (unsigned*)(w + 22192640);    // 8192000 uints
  const unsigned short* embh = (const unsigned short*)embbf;

  // zero: loss/cntA/cntB/c/hall-slot0 ; aall
  hipMemsetAsync(d_ws, 0, (size_t)34816*4, stream);
  hipMemsetAsync((void*)aall, 0, (size_t)96*512*4, stream);
  k_cvt_emb<<<8192,256,0,stream>>>(emb, embbf);
  k_setup<<<16,256,0,stream>>>(fe, nfp, e_k);
  k_pre_pa<<<dim3(256,64),256,0,stream>>>(Wih, fe, Pa);
  k_pre_ph<<<dim3(192,64),256,0,stream>>>(Wc1, Wv1, Wp1, fe, Ph);
  k_pre_pw<<<dim3(256,96),256,0,stream>>>(Wih, emb, tw, tz, bih, bhh, Pw);
  k_pre_cf<<<64,256,0,stream>>>(Wf1, bf1, e_k, cf);
  k_pre_g<<<dim3(64,4),256,0,stream>>>(Wf2, fe, Gb);
  k_gb0<<<16,256,0,stream>>>(fe, bf2, gb0);

  // phase 1: persistent kernel, all point-to-point spread-counter sync
  k_phase1<<<256,256,0,stream>>>(Whh, hall, Pw, Pa, aall, c, Wf1, cf, tf,
                                 Gb, gb0, ta, nfp, loss, cntA, cntB);

  k2_cvp<<<dim3(192,96),256,0,stream>>>(Wc1, Wv1, Wp1, hall, Ph, aall,
                                        bc1, bv1, bp1, tcvp);
  k2_heads2<<<dim3(40,96),256,0,stream>>>(Wv2, bv2, Wp2, bp2, Wc2, bc2,
                                          tcvp, kvh, kpall, zlall);
  k2_vocab<<<3000,256,0,stream>>>(embh, kvh, part);
  k2_vfin<<<1536,256,0,stream>>>(part, embh, kvh, tw, tz, loss);
  k2_posz<<<1536,128,0,stream>>>(kpall, zlall, WP, bP, pmask, tw, ta, tz, loss);
  k_out<<<1,1,0,stream>>>(loss, (float*)d_out);
}